// Round 1
// baseline (317.277 us; speedup 1.0000x reference)
//
#include <hip/hip_runtime.h>
#include <stdint.h>

typedef unsigned short u16;
typedef unsigned int u32;
typedef __attribute__((ext_vector_type(4))) float f32x4;
typedef __attribute__((ext_vector_type(8))) short short8;

#define H 8
#define LSEQ 2048
#define E 1024
#define DK 512
#define DVH 128
#define DKH 64
#define NCHUNK 32
#define MROWS 8192
#define LN_EPS 1e-5f

static __device__ __forceinline__ float bf2f(u16 u) {
    union { float f; u32 i; } v; v.i = ((u32)u) << 16; return v.f;
}
static __device__ __forceinline__ u16 f2bf(float f) {
    union { float f; u32 i; } v; v.f = f;
    u32 r = v.i + 0x7FFFu + ((v.i >> 16) & 1u);
    return (u16)(r >> 16);
}

// ---------------------------------------------------------------- conv+silu
__global__ __launch_bounds__(256) void k_conv(const float* __restrict__ x,
                                              const float* __restrict__ cw,
                                              u16* __restrict__ xc) {
    const int bl = blockIdx.x;           // b*L + l
    const int l  = bl & (LSEQ - 1);
    const int e0 = threadIdx.x * 4;
    const size_t base = (size_t)(bl - l) * E;   // b*L*E
    const f32x4 w0 = *(const f32x4*)(cw + (e0 + 0) * 4);
    const f32x4 w1 = *(const f32x4*)(cw + (e0 + 1) * 4);
    const f32x4 w2 = *(const f32x4*)(cw + (e0 + 2) * 4);
    const f32x4 w3 = *(const f32x4*)(cw + (e0 + 3) * 4);
    float a0 = 0.f, a1 = 0.f, a2 = 0.f, a3 = 0.f;
#pragma unroll
    for (int tap = 0; tap < 4; tap++) {
        const int r = l - 3 + tap;
        if (r >= 0) {
            const f32x4 xv = *(const f32x4*)(x + base + (size_t)r * E + e0);
            a0 = fmaf(xv[0], w0[tap], a0);
            a1 = fmaf(xv[1], w1[tap], a1);
            a2 = fmaf(xv[2], w2[tap], a2);
            a3 = fmaf(xv[3], w3[tap], a3);
        }
    }
    const float s0 = a0 / (1.f + __expf(-a0));
    const float s1 = a1 / (1.f + __expf(-a1));
    const float s2 = a2 / (1.f + __expf(-a2));
    const float s3 = a3 / (1.f + __expf(-a3));
    unsigned long long pk = (unsigned long long)f2bf(s0)
        | ((unsigned long long)f2bf(s1) << 16)
        | ((unsigned long long)f2bf(s2) << 32)
        | ((unsigned long long)f2bf(s3) << 48);
    *(unsigned long long*)(xc + (size_t)bl * E + e0) = pk;
}

// ------------------------------------------------- weight transpose + cast
// W [K][N] f32  ->  Wt [N][K] bf16
__global__ __launch_bounds__(256) void k_transpose(const float* __restrict__ W,
                                                   u16* __restrict__ Wt,
                                                   const int K, const int N) {
    __shared__ float tile[32][33];
    const int n0 = blockIdx.x * 32, k0 = blockIdx.y * 32;
    const int tx = threadIdx.x & 31, ty = threadIdx.x >> 5;   // ty 0..7
#pragma unroll
    for (int p = 0; p < 4; p++) {
        const int r = p * 8 + ty;
        tile[r][tx] = W[(size_t)(k0 + r) * N + n0 + tx];
    }
    __syncthreads();
#pragma unroll
    for (int p = 0; p < 4; p++) {
        const int rn = p * 8 + ty;
        Wt[(size_t)(n0 + rn) * K + k0 + tx] = f2bf(tile[tx][rn]);
    }
}

// ---------------------------------------------------------------- bf16 GEMM
// A [M,K] bf16 row-major, Bt [N,K] bf16 row-major (=B^T), 128x128 tile,
// BK=32, 4 waves (2x2 of 64x64), 16x16x32 MFMA. m97 structure.
// MODE 0: fused epilogue -> q / kg / v / sg=silu(g+bg), all bf16.
// MODE 1: f32 output (row stride N).
template <int MODE>
__global__ __launch_bounds__(256) void k_gemm(const u16* __restrict__ A,
                                              const u16* __restrict__ Bt,
                                              const int N, const int K,
                                              u16* __restrict__ oQ, u16* __restrict__ oKG,
                                              u16* __restrict__ oV, u16* __restrict__ oSG,
                                              const float* __restrict__ bg,
                                              float* __restrict__ oF) {
    __shared__ __align__(16) u16 As[128 * 32];
    __shared__ __align__(16) u16 Bs[128 * 32];
    const int tid = threadIdx.x;
    const int lane = tid & 63, wave = tid >> 6;
    const int wr = wave >> 1, wc = wave & 1;
    const size_t rowBase = (size_t)blockIdx.x * 128;
    const size_t colBase = (size_t)blockIdx.y * 128;
    f32x4 acc[4][4];
#pragma unroll
    for (int m = 0; m < 4; m++)
#pragma unroll
        for (int n = 0; n < 4; n++) acc[m][n] = (f32x4){0.f, 0.f, 0.f, 0.f};
    const int rsub = lane & 15;
    const int kq = (lane >> 4) * 8;

    for (int ko = 0; ko < K; ko += 32) {
        __syncthreads();
#pragma unroll
        for (int rr = 0; rr < 2; rr++) {
            const int chunk = rr * 4 + wave;          // 0..7, wave-uniform
            const int e0 = chunk * 512 + lane * 8;    // element in 128x32 tile
            const int r = e0 >> 5, c = e0 & 31;
            __builtin_amdgcn_global_load_lds(
                (const __attribute__((address_space(1))) void*)(A + (rowBase + r) * K + ko + c),
                (__attribute__((address_space(3))) void*)((char*)As + chunk * 1024), 16, 0, 0);
            __builtin_amdgcn_global_load_lds(
                (const __attribute__((address_space(1))) void*)(Bt + (colBase + r) * K + ko + c),
                (__attribute__((address_space(3))) void*)((char*)Bs + chunk * 1024), 16, 0, 0);
        }
        __syncthreads();
        short8 af[4], bfr[4];
#pragma unroll
        for (int m = 0; m < 4; m++)
            af[m] = *(const short8*)(As + (wr * 64 + m * 16 + rsub) * 32 + kq);
#pragma unroll
        for (int n = 0; n < 4; n++)
            bfr[n] = *(const short8*)(Bs + (wc * 64 + n * 16 + rsub) * 32 + kq);
#pragma unroll
        for (int m = 0; m < 4; m++)
#pragma unroll
            for (int n = 0; n < 4; n++)
                acc[m][n] = __builtin_amdgcn_mfma_f32_16x16x32_bf16(af[m], bfr[n], acc[m][n], 0, 0, 0);
    }

    const int r0 = (lane >> 4) * 4;
#pragma unroll
    for (int m = 0; m < 4; m++) {
#pragma unroll
        for (int n = 0; n < 4; n++) {
            const size_t col = colBase + wc * 64 + n * 16 + rsub;
#pragma unroll
            for (int r = 0; r < 4; r++) {
                const size_t row = rowBase + wr * 64 + m * 16 + r0 + r;
                const float val = acc[m][n][r];
                if (MODE == 1) {
                    oF[row * (size_t)N + col] = val;
                } else {
                    if (col < 512) oQ[row * 512 + col] = f2bf(val);
                    else if (col < 1024) oKG[row * 512 + (col - 512)] = f2bf(val);
                    else if (col < 2048) oV[row * 1024 + (col - 1024)] = f2bf(val);
                    else {
                        const float y = val + bg[col - 2048];
                        oSG[row * 1024 + (col - 2048)] = f2bf(y / (1.f + __expf(-y)));
                    }
                }
            }
        }
    }
}

// ------------------------------------------------------- GLA phase 1 (intra)
// grid (c=NCHUNK, bh=32), block 256. Computes per chunk:
//   O_intra (causal decayed attention), Sdelta, Dc, q~ (to qt), aug_w.
__global__ __launch_bounds__(256) void k_gla1(const u16* __restrict__ q,
                                              const u16* __restrict__ kg,
                                              const u16* __restrict__ v,
                                              const float* __restrict__ aug,
                                              u16* __restrict__ qt,
                                              u16* __restrict__ obuf,
                                              float* __restrict__ Sd,
                                              float* __restrict__ Dc,
                                              float* __restrict__ augw) {
    __shared__ __align__(16) float s_kt[64][68];   // gk, then k~ = k*exp(-L)
    __shared__ __align__(16) float s_gl[64][68];   // inclusive cumsum L
    __shared__ __align__(16) float s_qt[64][68];   // transposed [d][t], q~ = q*exp(L)*scale
    __shared__ __align__(16) float s_v[64][132];   // V chunk
    __shared__ __align__(16) float s_a[64][68];    // A^T [s][t]
    const int c = blockIdx.x, bh = blockIdx.y;
    const int b = bh >> 3, h = bh & 7;
    const int tid = threadIdx.x;
    const size_t rowBase = (size_t)b * LSEQ + c * 64;
    const size_t sdBase = (size_t)bh * NCHUNK + c;

    { // step 1: kg -> gk = log_sigmoid(kg)/16
        const int t = tid >> 2, d0 = (tid & 3) * 16;
        const u16* kp = kg + (rowBase + t) * DK + h * 64 + d0;
#pragma unroll
        for (int j = 0; j < 16; j++) {
            const float xk = bf2f(kp[j]);
            const float ls = fminf(xk, 0.f) - log1pf(__expf(-fabsf(xk)));
            s_kt[t][d0 + j] = ls * (1.f / 16.f);
        }
    }
    __syncthreads();
    if (tid < 64) { // step 2: cumsum over t (d-parallel, fully unrolled for ILP)
        float run = 0.f;
#pragma unroll
        for (int t = 0; t < 64; t++) { run += s_kt[t][tid]; s_gl[t][tid] = run; }
    }
    __syncthreads();
    { // step 3: k~, q~, aug_w, load V
        const int t = tid >> 2, d0 = (tid & 3) * 16;
        const u16* qp = q + (rowBase + t) * DK + h * 64 + d0;
        float qv[16];
        float augp = 0.f;
#pragma unroll
        for (int j = 0; j < 16; j++) {
            const int d = d0 + j;
            const float gkv = s_kt[t][d];
            const float Lv = s_gl[t][d];
            const float kk = 1.f - __expf(gkv);
            s_kt[t][d] = kk * __expf(-Lv);
            const float qraw = bf2f(qp[j]);
            const float qtv = qraw * __expf(Lv) * 0.125f;   // scale = 64^-0.5
            s_qt[d][t] = qtv;
            qv[j] = qtv;
            augp = fmaf(qraw * aug[h * 64 + d], kk, augp);
        }
        u16* qto = qt + (rowBase + t) * DK + h * 64 + d0;
#pragma unroll
        for (int j8 = 0; j8 < 16; j8 += 8) {
            uint4 u;
            u.x = (u32)f2bf(qv[j8 + 0]) | ((u32)f2bf(qv[j8 + 1]) << 16);
            u.y = (u32)f2bf(qv[j8 + 2]) | ((u32)f2bf(qv[j8 + 3]) << 16);
            u.z = (u32)f2bf(qv[j8 + 4]) | ((u32)f2bf(qv[j8 + 5]) << 16);
            u.w = (u32)f2bf(qv[j8 + 6]) | ((u32)f2bf(qv[j8 + 7]) << 16);
            *(uint4*)(qto + j8) = u;
        }
        augp += __shfl_xor(augp, 1);
        augp += __shfl_xor(augp, 2);
        if ((tid & 3) == 0) augw[(size_t)bh * LSEQ + c * 64 + t] = augp;

        const int dv0 = (tid & 3) * 32;
        const u16* vp = v + (rowBase + t) * E + h * 128 + dv0;
#pragma unroll
        for (int j8 = 0; j8 < 32; j8 += 8) {
            const uint4 u = *(const uint4*)(vp + j8);
            s_v[t][dv0 + j8 + 0] = bf2f((u16)(u.x & 0xffff));
            s_v[t][dv0 + j8 + 1] = bf2f((u16)(u.x >> 16));
            s_v[t][dv0 + j8 + 2] = bf2f((u16)(u.y & 0xffff));
            s_v[t][dv0 + j8 + 3] = bf2f((u16)(u.y >> 16));
            s_v[t][dv0 + j8 + 4] = bf2f((u16)(u.z & 0xffff));
            s_v[t][dv0 + j8 + 5] = bf2f((u16)(u.z >> 16));
            s_v[t][dv0 + j8 + 6] = bf2f((u16)(u.w & 0xffff));
            s_v[t][dv0 + j8 + 7] = bf2f((u16)(u.w >> 16));
        }
    }
    __syncthreads();
    { // step 4: A[t][s] = q~_t . k~_s   (causal)
        const int t = tid & 63;
        const int wvs = (tid >> 6) * 16;
        float qreg[64];
#pragma unroll
        for (int d = 0; d < 64; d++) qreg[d] = s_qt[d][t];
        for (int s = wvs; s < wvs + 16; s++) {
            if (s <= t) {
                float dot = 0.f;
#pragma unroll
                for (int d = 0; d < 64; d += 4) {
                    const f32x4 kv = *(const f32x4*)&s_kt[s][d];
                    dot = fmaf(qreg[d + 0], kv[0], dot);
                    dot = fmaf(qreg[d + 1], kv[1], dot);
                    dot = fmaf(qreg[d + 2], kv[2], dot);
                    dot = fmaf(qreg[d + 3], kv[3], dot);
                }
                s_a[s][t] = dot;
            }
        }
    }
    __syncthreads();
    { // step 5: O_intra[t] = sum_{s<=t} A[t][s] V[s]
        const int t = tid >> 2, dv0 = (tid & 3) * 32;
        float o[32];
#pragma unroll
        for (int j = 0; j < 32; j++) o[j] = 0.f;
        for (int s = 0; s <= t; s++) {
            const float a = s_a[s][t];
            const float* vr = &s_v[s][dv0];
#pragma unroll
            for (int j = 0; j < 32; j += 4) {
                const f32x4 vv = *(const f32x4*)(vr + j);
                o[j + 0] = fmaf(a, vv[0], o[j + 0]);
                o[j + 1] = fmaf(a, vv[1], o[j + 1]);
                o[j + 2] = fmaf(a, vv[2], o[j + 2]);
                o[j + 3] = fmaf(a, vv[3], o[j + 3]);
            }
        }
        u16* op = obuf + ((size_t)bh * LSEQ + c * 64 + t) * DVH + dv0;
#pragma unroll
        for (int j8 = 0; j8 < 32; j8 += 8) {
            uint4 u;
            u.x = (u32)f2bf(o[j8 + 0]) | ((u32)f2bf(o[j8 + 1]) << 16);
            u.y = (u32)f2bf(o[j8 + 2]) | ((u32)f2bf(o[j8 + 3]) << 16);
            u.z = (u32)f2bf(o[j8 + 4]) | ((u32)f2bf(o[j8 + 5]) << 16);
            u.w = (u32)f2bf(o[j8 + 6]) | ((u32)f2bf(o[j8 + 7]) << 16);
            *(uint4*)(op + j8) = u;
        }
    }
    { // step 6: Sdelta[d][dv] = exp(Lend[d]) * sum_s k~[s][d] V[s][dv] ; Dc[d]
        const int d = tid >> 2, dv0 = (tid & 3) * 32;
        float sd[32];
#pragma unroll
        for (int j = 0; j < 32; j++) sd[j] = 0.f;
        for (int s = 0; s < 64; s++) {
            const float kt = s_kt[s][d];
            const float* vr = &s_v[s][dv0];
#pragma unroll
            for (int j = 0; j < 32; j += 4) {
                const f32x4 vv = *(const f32x4*)(vr + j);
                sd[j + 0] = fmaf(kt, vv[0], sd[j + 0]);
                sd[j + 1] = fmaf(kt, vv[1], sd[j + 1]);
                sd[j + 2] = fmaf(kt, vv[2], sd[j + 2]);
                sd[j + 3] = fmaf(kt, vv[3], sd[j + 3]);
            }
        }
        const float dend = __expf(s_gl[63][d]);
        float* so = Sd + (sdBase * DKH + d) * DVH + dv0;
#pragma unroll
        for (int j = 0; j < 32; j += 4) {
            f32x4 w = { sd[j] * dend, sd[j + 1] * dend, sd[j + 2] * dend, sd[j + 3] * dend };
            *(f32x4*)(so + j) = w;
        }
        if ((tid & 3) == 0) Dc[sdBase * DKH + d] = dend;
    }
}

// ---------------------------------------------- GLA phase 2: chunk-state scan
// In-place on Sd: Sd[c] becomes S_start(c); run = Dc*run + delta.
__global__ __launch_bounds__(256) void k_gla2(float* __restrict__ Sd,
                                              const float* __restrict__ Dc) {
    const int cid = blockIdx.x * 256 + threadIdx.x;   // 0..262143
    const int bh = cid >> 13;
    const int e = cid & 8191;
    const int d = e >> 7;
    float run = 0.f;
    const size_t base = (size_t)bh * NCHUNK * 8192 + e;
    for (int c = 0; c < NCHUNK; c++) {
        const size_t idx = base + (size_t)c * 8192;
        const float dl = Sd[idx];
        Sd[idx] = run;
        run = fmaf(Dc[((size_t)bh * NCHUNK + c) * DKH + d], run, dl);
    }
}

// -------------------------- GLA phase 3: inter-chunk + aug + LN + silu-gate
__global__ __launch_bounds__(256) void k_gla3(const u16* __restrict__ qt,
                                              const u16* __restrict__ v,
                                              const u16* __restrict__ sg,
                                              const u16* __restrict__ obuf,
                                              const float* __restrict__ Ss,
                                              const float* __restrict__ augw,
                                              u16* __restrict__ a2) {
    __shared__ __align__(16) float s_S[64][132];
    __shared__ __align__(16) float s_qtT[64][68];
    const int c = blockIdx.x, bh = blockIdx.y;
    const int b = bh >> 3, h = bh & 7;
    const int tid = threadIdx.x;
    const size_t rowBase = (size_t)b * LSEQ + c * 64;
    {
        const int d = tid >> 2, dv0 = (tid & 3) * 32;
        const float* sp = Ss + (((size_t)bh * NCHUNK + c) * DKH + d) * DVH + dv0;
#pragma unroll
        for (int j = 0; j < 32; j += 4) *(f32x4*)&s_S[d][dv0 + j] = *(const f32x4*)(sp + j);
    }
    {
        const int t = tid >> 2, d0 = (tid & 3) * 16;
        const u16* qp = qt + (rowBase + t) * DK + h * 64 + d0;
#pragma unroll
        for (int j = 0; j < 16; j++) s_qtT[d0 + j][t] = bf2f(qp[j]);
    }
    __syncthreads();
    const int t = tid >> 2, dv0 = (tid & 3) * 32;
    float o[32];
    const u16* op = obuf + ((size_t)bh * LSEQ + c * 64 + t) * DVH + dv0;
#pragma unroll
    for (int j8 = 0; j8 < 32; j8 += 8) {
        const uint4 u = *(const uint4*)(op + j8);
        o[j8 + 0] = bf2f((u16)(u.x & 0xffff)); o[j8 + 1] = bf2f((u16)(u.x >> 16));
        o[j8 + 2] = bf2f((u16)(u.y & 0xffff)); o[j8 + 3] = bf2f((u16)(u.y >> 16));
        o[j8 + 4] = bf2f((u16)(u.z & 0xffff)); o[j8 + 5] = bf2f((u16)(u.z >> 16));
        o[j8 + 6] = bf2f((u16)(u.w & 0xffff)); o[j8 + 7] = bf2f((u16)(u.w >> 16));
    }
    for (int d = 0; d < 64; d++) {
        const float qv = s_qtT[d][t];
        const float* srow = &s_S[d][dv0];
#pragma unroll
        for (int j = 0; j < 32; j += 4) {
            const f32x4 sv = *(const f32x4*)(srow + j);
            o[j + 0] = fmaf(qv, sv[0], o[j + 0]);
            o[j + 1] = fmaf(qv, sv[1], o[j + 1]);
            o[j + 2] = fmaf(qv, sv[2], o[j + 2]);
            o[j + 3] = fmaf(qv, sv[3], o[j + 3]);
        }
    }
    const float aw = augw[(size_t)bh * LSEQ + c * 64 + t];
    const u16* vp = v + (rowBase + t) * E + h * 128 + dv0;
#pragma unroll
    for (int j8 = 0; j8 < 32; j8 += 8) {
        const uint4 u = *(const uint4*)(vp + j8);
        const float vv[8] = {
            bf2f((u16)(u.x & 0xffff)), bf2f((u16)(u.x >> 16)),
            bf2f((u16)(u.y & 0xffff)), bf2f((u16)(u.y >> 16)),
            bf2f((u16)(u.z & 0xffff)), bf2f((u16)(u.z >> 16)),
            bf2f((u16)(u.w & 0xffff)), bf2f((u16)(u.w >> 16)) };
#pragma unroll
        for (int j = 0; j < 8; j++)
            o[j8 + j] += 1.f / (1.f + __expf(-aw * vv[j]));
    }
    // LayerNorm over 128 (4 threads per row), two-pass for stability
    float sum = 0.f;
#pragma unroll
    for (int j = 0; j < 32; j++) sum += o[j];
    sum += __shfl_xor(sum, 1); sum += __shfl_xor(sum, 2);
    const float mu = sum * (1.f / 128.f);
    float sq = 0.f;
#pragma unroll
    for (int j = 0; j < 32; j++) { const float dlt = o[j] - mu; sq = fmaf(dlt, dlt, sq); }
    sq += __shfl_xor(sq, 1); sq += __shfl_xor(sq, 2);
    const float rs = rsqrtf(sq * (1.f / 128.f) + LN_EPS);
    const u16* sp2 = sg + (rowBase + t) * E + h * 128 + dv0;
    u16* ap = a2 + (rowBase + t) * E + h * 128 + dv0;
#pragma unroll
    for (int j8 = 0; j8 < 32; j8 += 8) {
        const uint4 us = *(const uint4*)(sp2 + j8);
        const float sv[8] = {
            bf2f((u16)(us.x & 0xffff)), bf2f((u16)(us.x >> 16)),
            bf2f((u16)(us.y & 0xffff)), bf2f((u16)(us.y >> 16)),
            bf2f((u16)(us.z & 0xffff)), bf2f((u16)(us.z >> 16)),
            bf2f((u16)(us.w & 0xffff)), bf2f((u16)(us.w >> 16)) };
        uint4 u;
        u.x = (u32)f2bf(sv[0] * ((o[j8 + 0] - mu) * rs)) | ((u32)f2bf(sv[1] * ((o[j8 + 1] - mu) * rs)) << 16);
        u.y = (u32)f2bf(sv[2] * ((o[j8 + 2] - mu) * rs)) | ((u32)f2bf(sv[3] * ((o[j8 + 3] - mu) * rs)) << 16);
        u.z = (u32)f2bf(sv[4] * ((o[j8 + 4] - mu) * rs)) | ((u32)f2bf(sv[5] * ((o[j8 + 5] - mu) * rs)) << 16);
        u.w = (u32)f2bf(sv[6] * ((o[j8 + 6] - mu) * rs)) | ((u32)f2bf(sv[7] * ((o[j8 + 7] - mu) * rs)) << 16);
        *(uint4*)(ap + j8) = u;
    }
}

// ----------------------------------------------------------------- launcher
extern "C" void kernel_launch(void* const* d_in, const int* in_sizes, int n_in,
                              void* d_out, int out_size, void* d_ws, size_t ws_size,
                              hipStream_t stream) {
    const float* x      = (const float*)d_in[0];
    const float* conv_w = (const float*)d_in[1];
    const float* wq     = (const float*)d_in[2];
    const float* wkg    = (const float*)d_in[3];
    const float* wv     = (const float*)d_in[4];
    const float* wg     = (const float*)d_in[5];
    const float* bg     = (const float*)d_in[6];
    const float* wout   = (const float*)d_in[7];
    const float* aug    = (const float*)d_in[8];

    char* ws = (char*)d_ws;
    size_t off = 0;
    auto alloc = [&](size_t bytes) -> char* {
        char* p = ws + off;
        off += (bytes + 255) & ~(size_t)255;
        return p;
    };
    u16* xc    = (u16*)alloc((size_t)MROWS * E * 2);          // 16.78 MB
    u16* wcat  = (u16*)alloc((size_t)3072 * E * 2);           //  6.29 MB
    u16* woutT = (u16*)alloc((size_t)E * E * 2);              //  2.10 MB
    u16* qb    = (u16*)alloc((size_t)MROWS * DK * 2);         //  8.39 MB
    u16* kgb   = (u16*)alloc((size_t)MROWS * DK * 2);         //  8.39 MB
    u16* vb    = (u16*)alloc((size_t)MROWS * E * 2);          // 16.78 MB
    u16* sgb   = (u16*)alloc((size_t)MROWS * E * 2);          // 16.78 MB
    u16* qtb   = (u16*)alloc((size_t)MROWS * DK * 2);         //  8.39 MB
    u16* obuf  = (u16*)alloc((size_t)32 * LSEQ * DVH * 2);    // 16.78 MB
    float* Dc  = (float*)alloc((size_t)32 * NCHUNK * DKH * 4);
    float* augw= (float*)alloc((size_t)32 * LSEQ * 4);
    u16* a2    = qb;                 // reuse q+kg region (q/kg dead after gla1)
    float* Sd  = (float*)d_out;      // 33.55 MB scratch; overwritten by final GEMM

    k_conv<<<MROWS, 256, 0, stream>>>(x, conv_w, xc);
    k_transpose<<<dim3(512 / 32, 1024 / 32), 256, 0, stream>>>(wq,  wcat + (size_t)0 * 1024,    1024, 512);
    k_transpose<<<dim3(512 / 32, 1024 / 32), 256, 0, stream>>>(wkg, wcat + (size_t)512 * 1024,  1024, 512);
    k_transpose<<<dim3(1024 / 32, 1024 / 32), 256, 0, stream>>>(wv,  wcat + (size_t)1024 * 1024, 1024, 1024);
    k_transpose<<<dim3(1024 / 32, 1024 / 32), 256, 0, stream>>>(wg,  wcat + (size_t)2048 * 1024, 1024, 1024);
    k_transpose<<<dim3(1024 / 32, 1024 / 32), 256, 0, stream>>>(wout, woutT, 1024, 1024);
    k_gemm<0><<<dim3(MROWS / 128, 3072 / 128), 256, 0, stream>>>(xc, wcat, 3072, 1024,
                                                                 qb, kgb, vb, sgb, bg, nullptr);
    k_gla1<<<dim3(NCHUNK, 32), 256, 0, stream>>>(qb, kgb, vb, aug, qtb, obuf, Sd, Dc, augw);
    k_gla2<<<1024, 256, 0, stream>>>(Sd, Dc);
    k_gla3<<<dim3(NCHUNK, 32), 256, 0, stream>>>(qtb, vb, sgb, obuf, Sd, augw, a2);
    k_gemm<1><<<dim3(MROWS / 128, 1024 / 128), 256, 0, stream>>>(a2, woutT, 1024, 1024,
                                                                 nullptr, nullptr, nullptr, nullptr,
                                                                 nullptr, (float*)d_out);
}

// Round 2
// 231.418 us; speedup vs baseline: 1.3710x; 1.3710x over previous
//
#include <hip/hip_runtime.h>
#include <stdint.h>

typedef unsigned short u16;
typedef unsigned int u32;
typedef __attribute__((ext_vector_type(4))) float f32x4;
typedef __attribute__((ext_vector_type(8))) short short8;
typedef __attribute__((ext_vector_type(8))) _Float16 f16x8;

#define H 8
#define LSEQ 2048
#define E 1024
#define DK 512
#define DVH 128
#define DKH 64
#define NCHUNK 32
#define MROWS 8192
#define LN_EPS 1e-5f

static __device__ __forceinline__ float bf2f(u16 u) {
    union { float f; u32 i; } v; v.i = ((u32)u) << 16; return v.f;
}
static __device__ __forceinline__ u16 f2bf(float f) {
    union { float f; u32 i; } v; v.f = f;
    u32 r = v.i + 0x7FFFu + ((v.i >> 16) & 1u);
    return (u16)(r >> 16);
}

// ---------------------------------------------------------------- conv+silu
__global__ __launch_bounds__(256) void k_conv(const float* __restrict__ x,
                                              const float* __restrict__ cw,
                                              u16* __restrict__ xc) {
    const int bl = blockIdx.x;           // b*L + l
    const int l  = bl & (LSEQ - 1);
    const int e0 = threadIdx.x * 4;
    const size_t base = (size_t)(bl - l) * E;   // b*L*E
    const f32x4 w0 = *(const f32x4*)(cw + (e0 + 0) * 4);
    const f32x4 w1 = *(const f32x4*)(cw + (e0 + 1) * 4);
    const f32x4 w2 = *(const f32x4*)(cw + (e0 + 2) * 4);
    const f32x4 w3 = *(const f32x4*)(cw + (e0 + 3) * 4);
    float a0 = 0.f, a1 = 0.f, a2 = 0.f, a3 = 0.f;
#pragma unroll
    for (int tap = 0; tap < 4; tap++) {
        const int r = l - 3 + tap;
        if (r >= 0) {
            const f32x4 xv = *(const f32x4*)(x + base + (size_t)r * E + e0);
            a0 = fmaf(xv[0], w0[tap], a0);
            a1 = fmaf(xv[1], w1[tap], a1);
            a2 = fmaf(xv[2], w2[tap], a2);
            a3 = fmaf(xv[3], w3[tap], a3);
        }
    }
    const float s0 = a0 / (1.f + __expf(-a0));
    const float s1 = a1 / (1.f + __expf(-a1));
    const float s2 = a2 / (1.f + __expf(-a2));
    const float s3 = a3 / (1.f + __expf(-a3));
    unsigned long long pk = (unsigned long long)f2bf(s0)
        | ((unsigned long long)f2bf(s1) << 16)
        | ((unsigned long long)f2bf(s2) << 32)
        | ((unsigned long long)f2bf(s3) << 48);
    *(unsigned long long*)(xc + (size_t)bl * E + e0) = pk;
}

// ------------------------------------------------- weight transpose + cast
__global__ __launch_bounds__(256) void k_transpose(const float* __restrict__ W,
                                                   u16* __restrict__ Wt,
                                                   const int K, const int N) {
    __shared__ float tile[32][33];
    const int n0 = blockIdx.x * 32, k0 = blockIdx.y * 32;
    const int tx = threadIdx.x & 31, ty = threadIdx.x >> 5;   // ty 0..7
#pragma unroll
    for (int p = 0; p < 4; p++) {
        const int r = p * 8 + ty;
        tile[r][tx] = W[(size_t)(k0 + r) * N + n0 + tx];
    }
    __syncthreads();
#pragma unroll
    for (int p = 0; p < 4; p++) {
        const int rn = p * 8 + ty;
        Wt[(size_t)(n0 + rn) * K + k0 + tx] = f2bf(tile[tx][rn]);
    }
}

// ---------------------------------------------------------------- bf16 GEMM
template <int MODE>
__global__ __launch_bounds__(256) void k_gemm(const u16* __restrict__ A,
                                              const u16* __restrict__ Bt,
                                              const int N, const int K,
                                              u16* __restrict__ oQ, u16* __restrict__ oKG,
                                              u16* __restrict__ oV, u16* __restrict__ oSG,
                                              const float* __restrict__ bg,
                                              float* __restrict__ oF) {
    __shared__ __align__(16) u16 As[128 * 32];
    __shared__ __align__(16) u16 Bs[128 * 32];
    const int tid = threadIdx.x;
    const int lane = tid & 63, wave = tid >> 6;
    const int wr = wave >> 1, wc = wave & 1;
    const size_t rowBase = (size_t)blockIdx.x * 128;
    const size_t colBase = (size_t)blockIdx.y * 128;
    f32x4 acc[4][4];
#pragma unroll
    for (int m = 0; m < 4; m++)
#pragma unroll
        for (int n = 0; n < 4; n++) acc[m][n] = (f32x4){0.f, 0.f, 0.f, 0.f};
    const int rsub = lane & 15;
    const int kq = (lane >> 4) * 8;

    for (int ko = 0; ko < K; ko += 32) {
        __syncthreads();
#pragma unroll
        for (int rr = 0; rr < 2; rr++) {
            const int chunk = rr * 4 + wave;          // 0..7, wave-uniform
            const int e0 = chunk * 512 + lane * 8;    // element in 128x32 tile
            const int r = e0 >> 5, c = e0 & 31;
            __builtin_amdgcn_global_load_lds(
                (const __attribute__((address_space(1))) void*)(A + (rowBase + r) * K + ko + c),
                (__attribute__((address_space(3))) void*)((char*)As + chunk * 1024), 16, 0, 0);
            __builtin_amdgcn_global_load_lds(
                (const __attribute__((address_space(1))) void*)(Bt + (colBase + r) * K + ko + c),
                (__attribute__((address_space(3))) void*)((char*)Bs + chunk * 1024), 16, 0, 0);
        }
        __syncthreads();
        short8 af[4], bfr[4];
#pragma unroll
        for (int m = 0; m < 4; m++)
            af[m] = *(const short8*)(As + (wr * 64 + m * 16 + rsub) * 32 + kq);
#pragma unroll
        for (int n = 0; n < 4; n++)
            bfr[n] = *(const short8*)(Bs + (wc * 64 + n * 16 + rsub) * 32 + kq);
#pragma unroll
        for (int m = 0; m < 4; m++)
#pragma unroll
            for (int n = 0; n < 4; n++)
                acc[m][n] = __builtin_amdgcn_mfma_f32_16x16x32_bf16(af[m], bfr[n], acc[m][n], 0, 0, 0);
    }

    const int r0 = (lane >> 4) * 4;
#pragma unroll
    for (int m = 0; m < 4; m++) {
#pragma unroll
        for (int n = 0; n < 4; n++) {
            const size_t col = colBase + wc * 64 + n * 16 + rsub;
#pragma unroll
            for (int r = 0; r < 4; r++) {
                const size_t row = rowBase + wr * 64 + m * 16 + r0 + r;
                const float val = acc[m][n][r];
                if (MODE == 1) {
                    oF[row * (size_t)N + col] = val;
                } else {
                    if (col < 512) oQ[row * 512 + col] = f2bf(val);
                    else if (col < 1024) oKG[row * 512 + (col - 512)] = f2bf(val);
                    else if (col < 2048) oV[row * 1024 + (col - 1024)] = f2bf(val);
                    else {
                        const float y = val + bg[col - 2048];
                        oSG[row * 1024 + (col - 2048)] = f2bf(y / (1.f + __expf(-y)));
                    }
                }
            }
        }
    }
}

// ------------------------------------------------------- GLA phase 1 (intra)
// MFMA fp16 version. grid (c=NCHUNK, bh=32), block 256 (4 waves).
// Per chunk: A = q~ k~^T (causal), O_intra = A V, Sdelta = k~^T V (scaled),
// plus q~ (to qt, bf16), aug_w, Dc.
__global__ __launch_bounds__(256) void k_gla1(const u16* __restrict__ q,
                                              const u16* __restrict__ kg,
                                              const u16* __restrict__ v,
                                              const float* __restrict__ aug,
                                              u16* __restrict__ qt,
                                              u16* __restrict__ obuf,
                                              float* __restrict__ Sd,
                                              float* __restrict__ Dc,
                                              float* __restrict__ augw) {
    __shared__ __align__(16) float    s_f[64][68];    // gk -> L (cumsum)
    __shared__ __align__(16) _Float16 s_q[64][72];    // q~ rows [t][d]
    __shared__ __align__(16) _Float16 s_k[64][72];    // k~ rows [s][d]
    __shared__ __align__(16) _Float16 s_kT[64][72];   // k~^T rows [d][s]
    __shared__ __align__(16) _Float16 s_a[64][72];    // temp k, then A [t][s]
    __shared__ __align__(16) _Float16 s_vT[128][72];  // V^T rows [dv][s]
    const int c = blockIdx.x, bh = blockIdx.y;
    const int b = bh >> 3, h = bh & 7;
    const int tid = threadIdx.x;
    const size_t rowBase = (size_t)b * LSEQ + c * 64;
    const size_t sdBase = (size_t)bh * NCHUNK + c;

    // ---- step A: gk = log_sigmoid(kg)/16 -> s_f ; V -> s_vT ; prefetch q
    const int tA = tid >> 2, g4 = tid & 3;
    uint4 qr0, qr1;
    {
        const int d0 = g4 * 16;
        const u16* kp = kg + (rowBase + tA) * DK + h * 64 + d0;
        const uint4 k0 = *(const uint4*)kp;
        const uint4 k1 = *(const uint4*)(kp + 8);
        const u16 kv[16] = {
            (u16)(k0.x & 0xffff), (u16)(k0.x >> 16), (u16)(k0.y & 0xffff), (u16)(k0.y >> 16),
            (u16)(k0.z & 0xffff), (u16)(k0.z >> 16), (u16)(k0.w & 0xffff), (u16)(k0.w >> 16),
            (u16)(k1.x & 0xffff), (u16)(k1.x >> 16), (u16)(k1.y & 0xffff), (u16)(k1.y >> 16),
            (u16)(k1.z & 0xffff), (u16)(k1.z >> 16), (u16)(k1.w & 0xffff), (u16)(k1.w >> 16) };
#pragma unroll
        for (int j = 0; j < 16; j++) {
            const float xk = bf2f(kv[j]);
            const float ls = fminf(xk, 0.f) - log1pf(__expf(-fabsf(xk)));
            s_f[tA][d0 + j] = ls * (1.f / 16.f);
        }
        const u16* qp = q + (rowBase + tA) * DK + h * 64 + d0;
        qr0 = *(const uint4*)qp;
        qr1 = *(const uint4*)(qp + 8);

        const int dv0 = g4 * 32;
        const u16* vp = v + (rowBase + tA) * E + h * 128 + dv0;
#pragma unroll
        for (int j8 = 0; j8 < 32; j8 += 8) {
            const uint4 u = *(const uint4*)(vp + j8);
            s_vT[dv0 + j8 + 0][tA] = (_Float16)bf2f((u16)(u.x & 0xffff));
            s_vT[dv0 + j8 + 1][tA] = (_Float16)bf2f((u16)(u.x >> 16));
            s_vT[dv0 + j8 + 2][tA] = (_Float16)bf2f((u16)(u.y & 0xffff));
            s_vT[dv0 + j8 + 3][tA] = (_Float16)bf2f((u16)(u.y >> 16));
            s_vT[dv0 + j8 + 4][tA] = (_Float16)bf2f((u16)(u.z & 0xffff));
            s_vT[dv0 + j8 + 5][tA] = (_Float16)bf2f((u16)(u.z >> 16));
            s_vT[dv0 + j8 + 6][tA] = (_Float16)bf2f((u16)(u.w & 0xffff));
            s_vT[dv0 + j8 + 7][tA] = (_Float16)bf2f((u16)(u.w >> 16));
        }
    }
    __syncthreads();

    // ---- step B: segmented cumsum over t per d; produce k~, k~^T, k, L
    {
        const int d = tid >> 2, qseg = tid & 3;
        float part = 0.f;
#pragma unroll
        for (int j = 0; j < 16; j++) part += s_f[qseg * 16 + j][d];
        float incl = part;
        const float u1 = __shfl_up(incl, 1, 4); if (qseg >= 1) incl += u1;
        const float u2 = __shfl_up(incl, 2, 4); if (qseg >= 2) incl += u2;
        float run = incl - part;   // exclusive prefix
#pragma unroll
        for (int j = 0; j < 16; j++) {
            const int t = qseg * 16 + j;
            const float g = s_f[t][d];
            run += g;
            const float kk = 1.f - __expf(g);
            const float ktil = kk * __expf(-run);
            s_k[t][d] = (_Float16)ktil;
            s_kT[d][t] = (_Float16)ktil;
            s_a[t][d] = (_Float16)kk;
            s_f[t][d] = run;    // L (inclusive)
        }
    }
    __syncthreads();

    // ---- step C: q~ (LDS f16 + global bf16), aug_w
    {
        const int t = tA, d0 = g4 * 16;
        const u16 qv16[16] = {
            (u16)(qr0.x & 0xffff), (u16)(qr0.x >> 16), (u16)(qr0.y & 0xffff), (u16)(qr0.y >> 16),
            (u16)(qr0.z & 0xffff), (u16)(qr0.z >> 16), (u16)(qr0.w & 0xffff), (u16)(qr0.w >> 16),
            (u16)(qr1.x & 0xffff), (u16)(qr1.x >> 16), (u16)(qr1.y & 0xffff), (u16)(qr1.y >> 16),
            (u16)(qr1.z & 0xffff), (u16)(qr1.z >> 16), (u16)(qr1.w & 0xffff), (u16)(qr1.w >> 16) };
        float qv[16];
        float augp = 0.f;
#pragma unroll
        for (int j = 0; j < 16; j++) {
            const int d = d0 + j;
            const float qraw = bf2f(qv16[j]);
            const float L = s_f[t][d];
            const float kk = (float)s_a[t][d];
            const float qtv = qraw * __expf(L) * 0.125f;   // scale 64^-0.5
            s_q[t][d] = (_Float16)qtv;
            qv[j] = qtv;
            augp = fmaf(qraw * aug[h * 64 + d], kk, augp);
        }
        u16* qto = qt + (rowBase + t) * DK + h * 64 + d0;
#pragma unroll
        for (int j8 = 0; j8 < 16; j8 += 8) {
            uint4 u;
            u.x = (u32)f2bf(qv[j8 + 0]) | ((u32)f2bf(qv[j8 + 1]) << 16);
            u.y = (u32)f2bf(qv[j8 + 2]) | ((u32)f2bf(qv[j8 + 3]) << 16);
            u.z = (u32)f2bf(qv[j8 + 4]) | ((u32)f2bf(qv[j8 + 5]) << 16);
            u.w = (u32)f2bf(qv[j8 + 6]) | ((u32)f2bf(qv[j8 + 7]) << 16);
            *(uint4*)(qto + j8) = u;
        }
        augp += __shfl_xor(augp, 1);
        augp += __shfl_xor(augp, 2);
        if ((tid & 3) == 0) augw[(size_t)bh * LSEQ + c * 64 + t] = augp;
    }
    __syncthreads();

    // ---- step D: A = q~ k~^T, causal mask, to s_a (f16). Wave w owns rows
    //      [w*16, w*16+16); computes col tiles si<=w, zero-fills si>w.
    const int wv = tid >> 6, lane = tid & 63;
    const int rsub = lane & 15, kq8 = (lane >> 4) * 8, r0 = (lane >> 4) * 4;
    {
#pragma unroll
        for (int si = 0; si < 4; si++) {
            if (si <= wv) {
                f32x4 acc = (f32x4){0.f, 0.f, 0.f, 0.f};
#pragma unroll
                for (int kk = 0; kk < 2; kk++) {
                    const f16x8 af = *(const f16x8*)&s_q[wv * 16 + rsub][kk * 32 + kq8];
                    const f16x8 bf = *(const f16x8*)&s_k[si * 16 + rsub][kk * 32 + kq8];
                    acc = __builtin_amdgcn_mfma_f32_16x16x32_f16(af, bf, acc, 0, 0, 0);
                }
                const int scol = si * 16 + rsub;
#pragma unroll
                for (int r = 0; r < 4; r++) {
                    const int trow = wv * 16 + r0 + r;
                    const float val = (scol <= trow) ? acc[r] : 0.f;
                    s_a[trow][scol] = (_Float16)val;
                }
            } else {
#pragma unroll
                for (int r = 0; r < 4; r++)
                    s_a[wv * 16 + r0 + r][si * 16 + rsub] = (_Float16)0.f;
            }
        }
    }
    __syncthreads();

    // ---- step E: O_intra = A V  (rows = wave's t-stripe, 8 dv tiles)
    {
        f32x4 oacc[8];
#pragma unroll
        for (int n = 0; n < 8; n++) oacc[n] = (f32x4){0.f, 0.f, 0.f, 0.f};
        const f16x8 a0 = *(const f16x8*)&s_a[wv * 16 + rsub][kq8];
        const f16x8 a1 = *(const f16x8*)&s_a[wv * 16 + rsub][32 + kq8];
#pragma unroll
        for (int n = 0; n < 8; n++) {
            const f16x8 b0 = *(const f16x8*)&s_vT[n * 16 + rsub][kq8];
            const f16x8 b1 = *(const f16x8*)&s_vT[n * 16 + rsub][32 + kq8];
            oacc[n] = __builtin_amdgcn_mfma_f32_16x16x32_f16(a0, b0, oacc[n], 0, 0, 0);
            oacc[n] = __builtin_amdgcn_mfma_f32_16x16x32_f16(a1, b1, oacc[n], 0, 0, 0);
        }
        u16* ob = obuf + ((size_t)bh * LSEQ + c * 64) * DVH;
#pragma unroll
        for (int n = 0; n < 8; n++) {
            const int dv = n * 16 + rsub;
#pragma unroll
            for (int r = 0; r < 4; r++) {
                const int trow = wv * 16 + r0 + r;
                ob[(size_t)trow * DVH + dv] = f2bf(oacc[n][r]);
            }
        }
    }

    // ---- step F: Sdelta = (k~^T V) * exp(Lend)  (rows = wave's d-stripe)
    {
        f32x4 sacc[8];
#pragma unroll
        for (int n = 0; n < 8; n++) sacc[n] = (f32x4){0.f, 0.f, 0.f, 0.f};
        const f16x8 a0 = *(const f16x8*)&s_kT[wv * 16 + rsub][kq8];
        const f16x8 a1 = *(const f16x8*)&s_kT[wv * 16 + rsub][32 + kq8];
#pragma unroll
        for (int n = 0; n < 8; n++) {
            const f16x8 b0 = *(const f16x8*)&s_vT[n * 16 + rsub][kq8];
            const f16x8 b1 = *(const f16x8*)&s_vT[n * 16 + rsub][32 + kq8];
            sacc[n] = __builtin_amdgcn_mfma_f32_16x16x32_f16(a0, b0, sacc[n], 0, 0, 0);
            sacc[n] = __builtin_amdgcn_mfma_f32_16x16x32_f16(a1, b1, sacc[n], 0, 0, 0);
        }
        float dend[4];
#pragma unroll
        for (int r = 0; r < 4; r++) dend[r] = __expf(s_f[63][wv * 16 + r0 + r]);
#pragma unroll
        for (int n = 0; n < 8; n++) {
            const int dv = n * 16 + rsub;
#pragma unroll
            for (int r = 0; r < 4; r++) {
                const int d = wv * 16 + r0 + r;
                Sd[(sdBase * DKH + d) * DVH + dv] = sacc[n][r] * dend[r];
            }
        }
        if (rsub == 0) {
#pragma unroll
            for (int r = 0; r < 4; r++) {
                const int d = wv * 16 + r0 + r;
                Dc[sdBase * DKH + d] = dend[r];
            }
        }
    }
}

// ---------------------------------------------- GLA phase 2: chunk-state scan
__global__ __launch_bounds__(256) void k_gla2(float* __restrict__ Sd,
                                              const float* __restrict__ Dc) {
    const int cid = blockIdx.x * 256 + threadIdx.x;   // 0..262143
    const int bh = cid >> 13;
    const int e = cid & 8191;
    const int d = e >> 7;
    float run = 0.f;
    const size_t base = (size_t)bh * NCHUNK * 8192 + e;
    for (int c = 0; c < NCHUNK; c++) {
        const size_t idx = base + (size_t)c * 8192;
        const float dl = Sd[idx];
        Sd[idx] = run;
        run = fmaf(Dc[((size_t)bh * NCHUNK + c) * DKH + d], run, dl);
    }
}

// -------------------------- GLA phase 3: inter-chunk + aug + LN + silu-gate
__global__ __launch_bounds__(256) void k_gla3(const u16* __restrict__ qt,
                                              const u16* __restrict__ v,
                                              const u16* __restrict__ sg,
                                              const u16* __restrict__ obuf,
                                              const float* __restrict__ Ss,
                                              const float* __restrict__ augw,
                                              u16* __restrict__ a2) {
    __shared__ __align__(16) float s_S[64][132];
    __shared__ __align__(16) float s_qtT[64][68];
    const int c = blockIdx.x, bh = blockIdx.y;
    const int b = bh >> 3, h = bh & 7;
    const int tid = threadIdx.x;
    const size_t rowBase = (size_t)b * LSEQ + c * 64;
    {
        const int d = tid >> 2, dv0 = (tid & 3) * 32;
        const float* sp = Ss + (((size_t)bh * NCHUNK + c) * DKH + d) * DVH + dv0;
#pragma unroll
        for (int j = 0; j < 32; j += 4) *(f32x4*)&s_S[d][dv0 + j] = *(const f32x4*)(sp + j);
    }
    {
        const int t = tid >> 2, d0 = (tid & 3) * 16;
        const u16* qp = qt + (rowBase + t) * DK + h * 64 + d0;
#pragma unroll
        for (int j = 0; j < 16; j++) s_qtT[d0 + j][t] = bf2f(qp[j]);
    }
    __syncthreads();
    const int t = tid >> 2, dv0 = (tid & 3) * 32;
    float o[32];
    const u16* op = obuf + ((size_t)bh * LSEQ + c * 64 + t) * DVH + dv0;
#pragma unroll
    for (int j8 = 0; j8 < 32; j8 += 8) {
        const uint4 u = *(const uint4*)(op + j8);
        o[j8 + 0] = bf2f((u16)(u.x & 0xffff)); o[j8 + 1] = bf2f((u16)(u.x >> 16));
        o[j8 + 2] = bf2f((u16)(u.y & 0xffff)); o[j8 + 3] = bf2f((u16)(u.y >> 16));
        o[j8 + 4] = bf2f((u16)(u.z & 0xffff)); o[j8 + 5] = bf2f((u16)(u.z >> 16));
        o[j8 + 6] = bf2f((u16)(u.w & 0xffff)); o[j8 + 7] = bf2f((u16)(u.w >> 16));
    }
    for (int d = 0; d < 64; d++) {
        const float qv = s_qtT[d][t];
        const float* srow = &s_S[d][dv0];
#pragma unroll
        for (int j = 0; j < 32; j += 4) {
            const f32x4 sv = *(const f32x4*)(srow + j);
            o[j + 0] = fmaf(qv, sv[0], o[j + 0]);
            o[j + 1] = fmaf(qv, sv[1], o[j + 1]);
            o[j + 2] = fmaf(qv, sv[2], o[j + 2]);
            o[j + 3] = fmaf(qv, sv[3], o[j + 3]);
        }
    }
    const float aw = augw[(size_t)bh * LSEQ + c * 64 + t];
    const u16* vp = v + (rowBase + t) * E + h * 128 + dv0;
#pragma unroll
    for (int j8 = 0; j8 < 32; j8 += 8) {
        const uint4 u = *(const uint4*)(vp + j8);
        const float vv[8] = {
            bf2f((u16)(u.x & 0xffff)), bf2f((u16)(u.x >> 16)),
            bf2f((u16)(u.y & 0xffff)), bf2f((u16)(u.y >> 16)),
            bf2f((u16)(u.z & 0xffff)), bf2f((u16)(u.z >> 16)),
            bf2f((u16)(u.w & 0xffff)), bf2f((u16)(u.w >> 16)) };
#pragma unroll
        for (int j = 0; j < 8; j++)
            o[j8 + j] += 1.f / (1.f + __expf(-aw * vv[j]));
    }
    // LayerNorm over 128 (4 threads per row)
    float sum = 0.f;
#pragma unroll
    for (int j = 0; j < 32; j++) sum += o[j];
    sum += __shfl_xor(sum, 1); sum += __shfl_xor(sum, 2);
    const float mu = sum * (1.f / 128.f);
    float sq = 0.f;
#pragma unroll
    for (int j = 0; j < 32; j++) { const float dlt = o[j] - mu; sq = fmaf(dlt, dlt, sq); }
    sq += __shfl_xor(sq, 1); sq += __shfl_xor(sq, 2);
    const float rs = rsqrtf(sq * (1.f / 128.f) + LN_EPS);
    const u16* sp2 = sg + (rowBase + t) * E + h * 128 + dv0;
    u16* ap = a2 + (rowBase + t) * E + h * 128 + dv0;
#pragma unroll
    for (int j8 = 0; j8 < 32; j8 += 8) {
        const uint4 us = *(const uint4*)(sp2 + j8);
        const float sv[8] = {
            bf2f((u16)(us.x & 0xffff)), bf2f((u16)(us.x >> 16)),
            bf2f((u16)(us.y & 0xffff)), bf2f((u16)(us.y >> 16)),
            bf2f((u16)(us.z & 0xffff)), bf2f((u16)(us.z >> 16)),
            bf2f((u16)(us.w & 0xffff)), bf2f((u16)(us.w >> 16)) };
        uint4 u;
        u.x = (u32)f2bf(sv[0] * ((o[j8 + 0] - mu) * rs)) | ((u32)f2bf(sv[1] * ((o[j8 + 1] - mu) * rs)) << 16);
        u.y = (u32)f2bf(sv[2] * ((o[j8 + 2] - mu) * rs)) | ((u32)f2bf(sv[3] * ((o[j8 + 3] - mu) * rs)) << 16);
        u.z = (u32)f2bf(sv[4] * ((o[j8 + 4] - mu) * rs)) | ((u32)f2bf(sv[5] * ((o[j8 + 5] - mu) * rs)) << 16);
        u.w = (u32)f2bf(sv[6] * ((o[j8 + 6] - mu) * rs)) | ((u32)f2bf(sv[7] * ((o[j8 + 7] - mu) * rs)) << 16);
        *(uint4*)(ap + j8) = u;
    }
}

// ----------------------------------------------------------------- launcher
extern "C" void kernel_launch(void* const* d_in, const int* in_sizes, int n_in,
                              void* d_out, int out_size, void* d_ws, size_t ws_size,
                              hipStream_t stream) {
    const float* x      = (const float*)d_in[0];
    const float* conv_w = (const float*)d_in[1];
    const float* wq     = (const float*)d_in[2];
    const float* wkg    = (const float*)d_in[3];
    const float* wv     = (const float*)d_in[4];
    const float* wg     = (const float*)d_in[5];
    const float* bg     = (const float*)d_in[6];
    const float* wout   = (const float*)d_in[7];
    const float* aug    = (const float*)d_in[8];

    char* ws = (char*)d_ws;
    size_t off = 0;
    auto alloc = [&](size_t bytes) -> char* {
        char* p = ws + off;
        off += (bytes + 255) & ~(size_t)255;
        return p;
    };
    u16* xc    = (u16*)alloc((size_t)MROWS * E * 2);
    u16* wcat  = (u16*)alloc((size_t)3072 * E * 2);
    u16* woutT = (u16*)alloc((size_t)E * E * 2);
    u16* qb    = (u16*)alloc((size_t)MROWS * DK * 2);
    u16* kgb   = (u16*)alloc((size_t)MROWS * DK * 2);
    u16* vb    = (u16*)alloc((size_t)MROWS * E * 2);
    u16* sgb   = (u16*)alloc((size_t)MROWS * E * 2);
    u16* qtb   = (u16*)alloc((size_t)MROWS * DK * 2);
    u16* obuf  = (u16*)alloc((size_t)32 * LSEQ * DVH * 2);
    float* Dc  = (float*)alloc((size_t)32 * NCHUNK * DKH * 4);
    float* augw= (float*)alloc((size_t)32 * LSEQ * 4);
    u16* a2    = qb;                 // reuse q+kg region (dead after gla1)
    float* Sd  = (float*)d_out;      // scratch; overwritten by final GEMM

    k_conv<<<MROWS, 256, 0, stream>>>(x, conv_w, xc);
    k_transpose<<<dim3(512 / 32, 1024 / 32), 256, 0, stream>>>(wq,  wcat + (size_t)0 * 1024,    1024, 512);
    k_transpose<<<dim3(512 / 32, 1024 / 32), 256, 0, stream>>>(wkg, wcat + (size_t)512 * 1024,  1024, 512);
    k_transpose<<<dim3(1024 / 32, 1024 / 32), 256, 0, stream>>>(wv,  wcat + (size_t)1024 * 1024, 1024, 1024);
    k_transpose<<<dim3(1024 / 32, 1024 / 32), 256, 0, stream>>>(wg,  wcat + (size_t)2048 * 1024, 1024, 1024);
    k_transpose<<<dim3(1024 / 32, 1024 / 32), 256, 0, stream>>>(wout, woutT, 1024, 1024);
    k_gemm<0><<<dim3(MROWS / 128, 3072 / 128), 256, 0, stream>>>(xc, wcat, 3072, 1024,
                                                                 qb, kgb, vb, sgb, bg, nullptr);
    k_gla1<<<dim3(NCHUNK, 32), 256, 0, stream>>>(qb, kgb, vb, aug, qtb, obuf, Sd, Dc, augw);
    k_gla2<<<1024, 256, 0, stream>>>(Sd, Dc);
    k_gla3<<<dim3(NCHUNK, 32), 256, 0, stream>>>(qtb, vb, sgb, obuf, Sd, augw, a2);
    k_gemm<1><<<dim3(MROWS / 128, 1024 / 128), 256, 0, stream>>>(a2, woutT, 1024, 1024,
                                                                 nullptr, nullptr, nullptr, nullptr,
                                                                 nullptr, (float*)d_out);
}